// Round 2
// baseline (434.975 us; speedup 1.0000x reference)
//
#include <hip/hip_runtime.h>

#define B_    1024
#define TI_   2
#define TE_   3
#define AB_   (TI_ * TE_)
#define BIN_  16
#define BOUT_ 32

// Generic body for NSH>=5: block handles NPB consecutive n for one ab.
// Thread = (o = tid&31, t = tid>>5); t indexes k-tiles of KT. W held in regs.
// acc[NSH][KT] -> LDS stage -> flat float4 flush (perfectly coalesced).
template<int NSH, int KT, int NPB>
__device__ __forceinline__ void conv_body(const float* __restrict__ X,
                                          const float* __restrict__ W,
                                          float* __restrict__ OUT,
                                          float* lds, int n0, int ab) {
    constexpr int NOUT  = BOUT_ * NSH * NSH;
    constexpr int TILES = (NSH + KT - 1) / KT;
    const int tid = threadIdx.x;
    const int o   = tid & 31;
    const int t   = tid >> 5;

    const float* Wp = W + ((size_t)ab * BIN_) * BOUT_ * NSH + o * NSH;

    float wv[BIN_][KT];
    if (t < TILES) {
#pragma unroll
        for (int i = 0; i < BIN_; ++i)
#pragma unroll
            for (int kk = 0; kk < KT; ++kk) {
                int k = t * KT + kk;
                if (k > NSH - 1) k = NSH - 1;   // clamp: valid addr, never stored
                wv[i][kk] = Wp[i * (BOUT_ * NSH) + k];
            }
    }

#pragma unroll
    for (int nn = 0; nn < NPB; ++nn) {
        const int n = n0 + nn;
        const float* Xp = X + ((size_t)n * AB_ + ab) * BIN_ * NSH;
        if (t < TILES) {
            float acc[NSH][KT];
#pragma unroll
            for (int l = 0; l < NSH; ++l)
#pragma unroll
                for (int kk = 0; kk < KT; ++kk) acc[l][kk] = 0.0f;

#pragma unroll
            for (int i = 0; i < BIN_; ++i) {
                float xv[NSH];
#pragma unroll
                for (int l = 0; l < NSH; ++l) xv[l] = Xp[i * NSH + l];  // wave-uniform
#pragma unroll
                for (int l = 0; l < NSH; ++l)
#pragma unroll
                    for (int kk = 0; kk < KT; ++kk)
                        acc[l][kk] = fmaf(xv[l], wv[i][kk], acc[l][kk]);
            }
#pragma unroll
            for (int l = 0; l < NSH; ++l)
#pragma unroll
                for (int kk = 0; kk < KT; ++kk) {
                    int k = t * KT + kk;
                    if (k < NSH) lds[nn * NOUT + (o * NSH + l) * NSH + k] = acc[l][kk];
                }
        }
    }
    __syncthreads();

#pragma unroll
    for (int nn = 0; nn < NPB; ++nn) {
        float4* dst = (float4*)(OUT + ((size_t)(n0 + nn) * AB_ + ab) * NOUT);
        const float4* src = (const float4*)(lds + nn * NOUT);
        constexpr int NC = NOUT / 4;
        for (int c = tid; c < NC; c += 256) dst[c] = src[c];
    }
}

// l=0 special case: direct coalesced stores, no LDS. 64 n per block.
__device__ __forceinline__ void conv_l0(const float* __restrict__ X,
                                        const float* __restrict__ W,
                                        const float* __restrict__ bias,
                                        float* __restrict__ OUT, int n0, int ab) {
    const int o  = threadIdx.x & 31;
    const int ns = threadIdx.x >> 5;  // 0..7
    float wv[BIN_];
#pragma unroll
    for (int i = 0; i < BIN_; ++i) wv[i] = W[(ab * BIN_ + i) * BOUT_ + o];
    const float bv = bias[ab * BOUT_ + o];
#pragma unroll
    for (int s = 0; s < 8; ++s) {
        const int n = n0 + ns + s * 8;
        const float* Xp = X + ((size_t)n * AB_ + ab) * BIN_;
        float acc = bv;
#pragma unroll
        for (int i = 0; i < BIN_; ++i) acc = fmaf(Xp[i], wv[i], acc);
        OUT[((size_t)n * AB_ + ab) * BOUT_ + o] = acc;
    }
}

#define NB8 (B_ * AB_)            // 6144, NPB=1
#define NB6 (B_ * AB_)            // 6144, NPB=1
#define NB4 ((B_ / 2) * AB_)      // 3072, NPB=2
#define NB2 ((B_ / 4) * AB_)      // 1536, NPB=4
#define NB0 ((B_ / 64) * AB_)     //   96, 64 n/block

__global__ __launch_bounds__(256)
void s2conv_fused(const float* __restrict__ x0, const float* __restrict__ x2,
                  const float* __restrict__ x4, const float* __restrict__ x6,
                  const float* __restrict__ x8,
                  const float* __restrict__ w0, const float* __restrict__ w2,
                  const float* __restrict__ w4, const float* __restrict__ w6,
                  const float* __restrict__ w8,
                  const float* __restrict__ bias, float* __restrict__ out,
                  size_t off0, size_t off2, size_t off4, size_t off6, size_t off8) {
    __shared__ __align__(16) float lds[BOUT_ * 17 * 17];  // 37 KB, max over degrees
    int b = blockIdx.x;
    if (b < NB8) {
        conv_body<17, 3, 1>(x8, w8, out + off8, lds, b / AB_, b % AB_);
        return;
    }
    b -= NB8;
    if (b < NB6) {
        conv_body<13, 2, 1>(x6, w6, out + off6, lds, b / AB_, b % AB_);
        return;
    }
    b -= NB6;
    if (b < NB4) {
        conv_body<9, 2, 2>(x4, w4, out + off4, lds, (b / AB_) * 2, b % AB_);
        return;
    }
    b -= NB4;
    if (b < NB2) {
        conv_body<5, 1, 4>(x2, w2, out + off2, lds, (b / AB_) * 4, b % AB_);
        return;
    }
    b -= NB2;
    conv_l0(x0, w0, bias, out + off0, (b / AB_) * 64, b % AB_);
}

extern "C" void kernel_launch(void* const* d_in, const int* in_sizes, int n_in,
                              void* d_out, int out_size, void* d_ws, size_t ws_size,
                              hipStream_t stream) {
    const float* x0 = (const float*)d_in[0];
    const float* w0 = (const float*)d_in[1];
    const float* x2 = (const float*)d_in[2];
    const float* w2 = (const float*)d_in[3];
    const float* x4 = (const float*)d_in[4];
    const float* w4 = (const float*)d_in[5];
    const float* x6 = (const float*)d_in[6];
    const float* w6 = (const float*)d_in[7];
    const float* x8 = (const float*)d_in[8];
    const float* w8 = (const float*)d_in[9];
    const float* bias = (const float*)d_in[10];
    float* out = (float*)d_out;

    const size_t per = (size_t)B_ * AB_ * BOUT_;  // elements per (l,k) slot
    size_t off0 = 0;
    size_t off2 = off0 + per * 1;
    size_t off4 = off2 + per * 25;
    size_t off6 = off4 + per * 81;
    size_t off8 = off6 + per * 169;

    const int nblocks = NB8 + NB6 + NB4 + NB2 + NB0;
    s2conv_fused<<<nblocks, 256, 0, stream>>>(x0, x2, x4, x6, x8,
                                              w0, w2, w4, w6, w8,
                                              bias, out,
                                              off0, off2, off4, off6, off8);
}

// Round 3
// 379.520 us; speedup vs baseline: 1.1461x; 1.1461x over previous
//
#include <hip/hip_runtime.h>

#define B_    1024
#define TI_   2
#define TE_   3
#define AB_   (TI_ * TE_)
#define BIN_  16
#define BOUT_ 32

// extract element L (compile-time after unroll) from a float4 array
#define XGET(q, L) (((L) & 3) == 0 ? q[(L) >> 2].x : \
                    ((L) & 3) == 1 ? q[(L) >> 2].y : \
                    ((L) & 3) == 2 ? q[(L) >> 2].z : q[(L) >> 2].w)

// out[slice, o, l, k] = sum_i X[slice, i, l] * W[ab, i, o, k],  slice = n*AB+ab
// Thread: (o = lane&31, k-tile kt = wis*2 + lane>>5, k0 = kt*KT), acc[NSH][KT].
// X staged in LDS (broadcast b128 reads); W hoisted to registers once; direct
// dword stores with compile-time offset folding.
template<int NSH, int KT, int WPS, int SPB>
__global__ __launch_bounds__(WPS * SPB * 64, 2)
void conv_kernel(const float* __restrict__ X, const float* __restrict__ W,
                 float* __restrict__ OUT) {
    constexpr int LP     = ((NSH + 3) / 4) * 4;   // padded X row, float4 multiple
    constexpr int CH     = LP / 4;                // float4 chunks per row
    constexpr int BLOCK  = WPS * SPB * 64;
    __shared__ __align__(16) float xs[SPB][BIN_][LP];

    const int tid  = threadIdx.x;
    const int wv_  = tid >> 6;          // wave in block
    const int lane = tid & 63;
    const int sl   = wv_ / WPS;         // slice within block
    const int wis  = wv_ % WPS;         // wave within slice
    const int o    = lane & 31;
    const int k0   = (wis * 2 + (lane >> 5)) * KT;

    const int slice0 = blockIdx.x * SPB;

    // ---- stage X for this block's SPB slices (contiguous in memory) ----
    {
        const float* Xg = X + (size_t)slice0 * BIN_ * NSH;
        constexpr int NE = SPB * BIN_ * NSH;
        for (int e = tid; e < NE; e += BLOCK) {
            int s = e / (BIN_ * NSH);
            int r = e % (BIN_ * NSH);
            xs[s][r / NSH][r % NSH] = Xg[e];
        }
    }
    __syncthreads();

    const int slice = slice0 + sl;
    const int ab    = slice % AB_;

    // ---- hoist W column (this thread's KT k's, all i) into registers ----
    const float* Wp = W + ((size_t)ab * BIN_ * BOUT_ + o) * NSH;
    float wreg[BIN_][KT];
#pragma unroll
    for (int i = 0; i < BIN_; ++i)
#pragma unroll
        for (int kk = 0; kk < KT; ++kk) {
            int k = k0 + kk;
            if (k > NSH - 1) k = NSH - 1;   // clamp: valid addr, never stored
            wreg[i][kk] = Wp[i * (BOUT_ * NSH) + k];
        }

    // ---- accumulate ----
    float acc[NSH][KT];
#pragma unroll
    for (int l = 0; l < NSH; ++l)
#pragma unroll
        for (int kk = 0; kk < KT; ++kk) acc[l][kk] = 0.0f;

#pragma unroll
    for (int i = 0; i < BIN_; ++i) {
        float4 xq[CH];
#pragma unroll
        for (int c = 0; c < CH; ++c)
            xq[c] = *(const float4*)&xs[sl][i][c * 4];   // wave-uniform broadcast
#pragma unroll
        for (int l = 0; l < NSH; ++l) {
            const float xv = XGET(xq, l);
#pragma unroll
            for (int kk = 0; kk < KT; ++kk)
                acc[l][kk] = fmaf(xv, wreg[i][kk], acc[l][kk]);
        }
    }

    // ---- direct stores, compile-time offsets fold into the instruction ----
    float* Op = OUT + (size_t)slice * (BOUT_ * NSH * NSH) + (size_t)o * (NSH * NSH) + k0;
#pragma unroll
    for (int kk = 0; kk < KT; ++kk) {
        if (k0 + kk < NSH) {
#pragma unroll
            for (int l = 0; l < NSH; ++l)
                Op[l * NSH + kk] = acc[l][kk];
        }
    }
}

// l=0: direct coalesced stores, 64 n per block.
__global__ __launch_bounds__(256)
void conv_l0_kernel(const float* __restrict__ X, const float* __restrict__ W,
                    const float* __restrict__ bias, float* __restrict__ OUT) {
    const int o  = threadIdx.x & 31;
    const int ns = threadIdx.x >> 5;   // 0..7
    const int b  = blockIdx.x;
    const int n0 = (b / AB_) * 64;
    const int ab = b % AB_;
    float wv[BIN_];
#pragma unroll
    for (int i = 0; i < BIN_; ++i) wv[i] = W[(ab * BIN_ + i) * BOUT_ + o];
    const float bv = bias[ab * BOUT_ + o];
#pragma unroll
    for (int s = 0; s < 8; ++s) {
        const int n = n0 + ns + s * 8;
        const float* Xp = X + ((size_t)n * AB_ + ab) * BIN_;
        float acc = bv;
#pragma unroll
        for (int i = 0; i < BIN_; ++i) acc = fmaf(Xp[i], wv[i], acc);
        OUT[((size_t)n * AB_ + ab) * BOUT_ + o] = acc;
    }
}

extern "C" void kernel_launch(void* const* d_in, const int* in_sizes, int n_in,
                              void* d_out, int out_size, void* d_ws, size_t ws_size,
                              hipStream_t stream) {
    const float* x0 = (const float*)d_in[0];
    const float* w0 = (const float*)d_in[1];
    const float* x2 = (const float*)d_in[2];
    const float* w2 = (const float*)d_in[3];
    const float* x4 = (const float*)d_in[4];
    const float* w4 = (const float*)d_in[5];
    const float* x6 = (const float*)d_in[6];
    const float* w6 = (const float*)d_in[7];
    const float* x8 = (const float*)d_in[8];
    const float* w8 = (const float*)d_in[9];
    const float* bias = (const float*)d_in[10];
    float* out = (float*)d_out;

    const size_t per = (size_t)B_ * AB_ * BOUT_;
    size_t off0 = 0;
    size_t off2 = off0 + per * 1;
    size_t off4 = off2 + per * 25;
    size_t off6 = off4 + per * 81;
    size_t off8 = off6 + per * 169;

    const int S = B_ * AB_;  // 6144 slices

    // NSH, KT, waves-per-slice, slices-per-block
    conv_kernel<17, 3, 3, 1><<<S,     192, 0, stream>>>(x8, w8, out + off8);
    conv_kernel<13, 2, 4, 1><<<S,     256, 0, stream>>>(x6, w6, out + off6);
    conv_kernel< 9, 5, 1, 4><<<S / 4, 256, 0, stream>>>(x4, w4, out + off4);
    conv_kernel< 5, 3, 1, 4><<<S / 4, 256, 0, stream>>>(x2, w2, out + off2);
    conv_l0_kernel<<<(B_ / 64) * AB_, 256, 0, stream>>>(x0, w0, bias, out + off0);
}

// Round 4
// 357.404 us; speedup vs baseline: 1.2170x; 1.0619x over previous
//
#include <hip/hip_runtime.h>

#define B_    1024
#define TI_   2
#define TE_   3
#define AB_   (TI_ * TE_)
#define BIN_  16
#define BOUT_ 32

// out[slice, o, l, k] = sum_i X[slice, i, l] * W[ab, i, o, k],  slice = n*AB+ab
//
// TPS threads own one slice: o = tid&31, t = (tid&(TPS-1))>>5, k-tile [t*KT, t*KT+KT).
// SPB slices per 256-thread block (slices flat-consecutive -> contiguous flush).
// X: block/wave-uniform global loads (compiler -> s_load broadcast; no guards).
// W: hoisted to VGPRs once per slice (clamped tail k, uniform control flow).
// Output: acc regs -> LDS tile -> flat float4 flush (perfect coalescing).
template<int NSH, int KT, int TPS, int SPB, int MINW>
__global__ __launch_bounds__(256, MINW)
void conv_kernel(const float* __restrict__ X, const float* __restrict__ W,
                 float* __restrict__ OUT) {
    constexpr int NOUT = BOUT_ * NSH * NSH;
    __shared__ __align__(16) float lds[SPB * NOUT];

    const int tid = threadIdx.x;
    const int o   = tid & 31;
    const int t   = (tid & (TPS - 1)) >> 5;
    const int k0  = t * KT;

    int sl = 0;
    if (SPB > 1) sl = __builtin_amdgcn_readfirstlane(tid / TPS);  // wave-uniform
    const int slice = blockIdx.x * SPB + sl;
    const int ab    = slice % AB_;

    // ---- hoist W column (this thread's KT k's, all i) into VGPRs ----
    const float* Wp = W + ((size_t)ab * BIN_ * BOUT_ + o) * NSH;
    float wreg[BIN_][KT];
#pragma unroll
    for (int i = 0; i < BIN_; ++i)
#pragma unroll
        for (int kk = 0; kk < KT; ++kk) {
            int k = k0 + kk;
            if (k > NSH - 1) k = NSH - 1;   // clamp: valid addr, never stored
            wreg[i][kk] = Wp[(size_t)i * (BOUT_ * NSH) + k];
        }

    // ---- accumulate; X loads are uniform -> scalar broadcast ----
    const float* Xp = X + (size_t)slice * (BIN_ * NSH);
    float acc[NSH][KT] = {};
#pragma unroll 2
    for (int i = 0; i < BIN_; ++i) {
        float xv[NSH];
#pragma unroll
        for (int l = 0; l < NSH; ++l) xv[l] = Xp[i * NSH + l];
#pragma unroll
        for (int l = 0; l < NSH; ++l)
#pragma unroll
            for (int kk = 0; kk < KT; ++kk)
                acc[l][kk] = fmaf(xv[l], wreg[i][kk], acc[l][kk]);
    }

    // ---- stage (o,l,k) tile in LDS (o-stride NSH*NSH odd -> <=2-way, free) ----
    float* ls = lds + sl * NOUT + (size_t)o * (NSH * NSH) + k0;
#pragma unroll
    for (int l = 0; l < NSH; ++l)
#pragma unroll
        for (int kk = 0; kk < KT; ++kk)
            if (k0 + kk < NSH) ls[l * NSH + kk] = acc[l][kk];
    __syncthreads();

    // ---- flat float4 flush: SPB consecutive slices = one contiguous range ----
    float4* dst = (float4*)(OUT + (size_t)blockIdx.x * SPB * NOUT);
    const float4* src = (const float4*)lds;
    constexpr int NC = SPB * NOUT / 4;
    for (int c = tid; c < NC; c += 256) dst[c] = src[c];
}

// l=0: direct coalesced stores, 64 n per block.
__global__ __launch_bounds__(256)
void conv_l0_kernel(const float* __restrict__ X, const float* __restrict__ W,
                    const float* __restrict__ bias, float* __restrict__ OUT) {
    const int o  = threadIdx.x & 31;
    const int ns = threadIdx.x >> 5;   // 0..7
    const int b  = blockIdx.x;
    const int n0 = (b / AB_) * 64;
    const int ab = b % AB_;
    float wv[BIN_];
#pragma unroll
    for (int i = 0; i < BIN_; ++i) wv[i] = W[(ab * BIN_ + i) * BOUT_ + o];
    const float bv = bias[ab * BOUT_ + o];
#pragma unroll
    for (int s = 0; s < 8; ++s) {
        const int n = n0 + ns + s * 8;
        const float* Xp = X + ((size_t)n * AB_ + ab) * BIN_;
        float acc = bv;
#pragma unroll
        for (int i = 0; i < BIN_; ++i) acc = fmaf(Xp[i], wv[i], acc);
        OUT[((size_t)n * AB_ + ab) * BOUT_ + o] = acc;
    }
}

extern "C" void kernel_launch(void* const* d_in, const int* in_sizes, int n_in,
                              void* d_out, int out_size, void* d_ws, size_t ws_size,
                              hipStream_t stream) {
    const float* x0 = (const float*)d_in[0];
    const float* w0 = (const float*)d_in[1];
    const float* x2 = (const float*)d_in[2];
    const float* w2 = (const float*)d_in[3];
    const float* x4 = (const float*)d_in[4];
    const float* w4 = (const float*)d_in[5];
    const float* x6 = (const float*)d_in[6];
    const float* w6 = (const float*)d_in[7];
    const float* x8 = (const float*)d_in[8];
    const float* w8 = (const float*)d_in[9];
    const float* bias = (const float*)d_in[10];
    float* out = (float*)d_out;

    const size_t per = (size_t)B_ * AB_ * BOUT_;
    size_t off0 = 0;
    size_t off2 = off0 + per * 1;
    size_t off4 = off2 + per * 25;
    size_t off6 = off4 + per * 81;
    size_t off8 = off6 + per * 169;

    const int S = B_ * AB_;  // 6144 slices

    //           NSH KT TPS SPB MINW     grid
    conv_kernel<17, 3, 256, 1, 3><<<S,     256, 0, stream>>>(x8, w8, out + off8);
    conv_kernel<13, 2, 256, 1, 4><<<S,     256, 0, stream>>>(x6, w6, out + off6);
    conv_kernel< 9, 3, 128, 2, 4><<<S / 2, 256, 0, stream>>>(x4, w4, out + off4);
    conv_kernel< 5, 3,  64, 4, 4><<<S / 4, 256, 0, stream>>>(x2, w2, out + off2);
    conv_l0_kernel<<<(B_ / 64) * AB_, 256, 0, stream>>>(x0, w0, bias, out + off0);
}

// Round 5
// 167.393 us; speedup vs baseline: 2.5985x; 2.1351x over previous
//
#include <hip/hip_runtime.h>

#define B_    1024
#define TI_   2
#define TE_   3
#define AB_   (TI_ * TE_)
#define BIN_  16
#define BOUT_ 32

typedef float f2 __attribute__((ext_vector_type(2)));
typedef float f4 __attribute__((ext_vector_type(4)));

// out[slice, o, l, k] = sum_i X[slice, i, l] * W[ab, i, o, k],  slice = n*AB+ab
//
// One thread per (slice-in-block, o, k): zero k-waste, W loads coalesced
// (addr == consecutive wid). X staged in LDS once (coalesced), inner loop
// reads it as broadcast ds_read_b128. l-accumulators packed in float2 ->
// v_pk_fma_f32 (2 FMA/lane/instr). Output via LDS tile + flat float4 flush.
template<int NSH, int SPB, int BLOCK>
__global__ __launch_bounds__(BLOCK)
void conv_pk(const float* __restrict__ X, const float* __restrict__ W,
             float* __restrict__ OUT) {
    constexpr int TS    = BOUT_ * NSH;          // threads per slice
    constexpr int LP    = ((NSH + 3) / 4) * 4;  // padded X row (float4 mult, even)
    constexpr int PAIRS = (NSH + 1) / 2;
    constexpr int NOUT  = BOUT_ * NSH * NSH;

    __shared__ __attribute__((aligned(16))) float xs[SPB * BIN_ * LP];
    __shared__ __attribute__((aligned(16))) float os[SPB * NOUT];

    const int tid = threadIdx.x;

    // ---- stage X (pad slots zeroed so packed-pair tails stay finite) ----
    {
        const float* Xg = X + (size_t)blockIdx.x * (SPB * BIN_ * NSH);
        for (int e = tid; e < SPB * BIN_ * LP; e += BLOCK) {
            int i = e / LP;      // fused (slice,row) index
            int l = e % LP;
            xs[e] = (l < NSH) ? Xg[i * NSH + l] : 0.0f;
        }
    }
    __syncthreads();

    if (tid < SPB * TS) {
        const int sl  = tid / TS;
        const int wid = tid - sl * TS;
        const int o   = wid / NSH;          // compile-time const divisor -> magic mul
        const int k   = wid - o * NSH;
        const int slice = blockIdx.x * SPB + sl;
        const int ab    = slice % AB_;

        // ---- hoist W column (this thread's single k, all i); coalesced ----
        const float* Wp = W + (size_t)ab * (BIN_ * BOUT_ * NSH) + o * NSH + k;
        f2 wreg[BIN_];
#pragma unroll
        for (int i = 0; i < BIN_; ++i) {
            float w = Wp[i * (BOUT_ * NSH)];
            wreg[i].x = w; wreg[i].y = w;
        }

        f2 acc[PAIRS];
#pragma unroll
        for (int p = 0; p < PAIRS; ++p) { acc[p].x = 0.0f; acc[p].y = 0.0f; }

        const float* xrow = xs + sl * (BIN_ * LP);
#pragma unroll
        for (int i = 0; i < BIN_; ++i) {
            f4 q[LP / 4];
#pragma unroll
            for (int c = 0; c < LP / 4; ++c)
                q[c] = *(const f4*)(xrow + i * LP + 4 * c);   // broadcast b128
#pragma unroll
            for (int p = 0; p < PAIRS; ++p) {
                f2 xp = (p & 1) ? __builtin_shufflevector(q[p >> 1], q[p >> 1], 2, 3)
                                : __builtin_shufflevector(q[p >> 1], q[p >> 1], 0, 1);
                acc[p] = __builtin_elementwise_fma(xp, wreg[i], acc[p]);  // v_pk_fma_f32
            }
        }

        // ---- stage (o,l,k) tile; addr stride pattern is <=2-way (free) ----
        float* op = os + sl * NOUT + (o * NSH) * NSH + k;
#pragma unroll
        for (int l = 0; l < NSH; ++l)
            op[l * NSH] = (l & 1) ? acc[l >> 1].y : acc[l >> 1].x;
    }
    __syncthreads();

    // ---- flat float4 flush: SPB consecutive slices = contiguous range ----
    f4* dst = (f4*)(OUT + (size_t)blockIdx.x * (SPB * NOUT));
    const f4* src = (const f4*)os;
    constexpr int NC = SPB * NOUT / 4;
    for (int c = tid; c < NC; c += BLOCK) dst[c] = src[c];
}

// l=0: direct coalesced stores, 64 n per block.
__global__ __launch_bounds__(256)
void conv_l0_kernel(const float* __restrict__ X, const float* __restrict__ W,
                    const float* __restrict__ bias, float* __restrict__ OUT) {
    const int o  = threadIdx.x & 31;
    const int ns = threadIdx.x >> 5;   // 0..7
    const int b  = blockIdx.x;
    const int n0 = (b / AB_) * 64;
    const int ab = b % AB_;
    float wv[BIN_];
#pragma unroll
    for (int i = 0; i < BIN_; ++i) wv[i] = W[(ab * BIN_ + i) * BOUT_ + o];
    const float bv = bias[ab * BOUT_ + o];
#pragma unroll
    for (int s = 0; s < 8; ++s) {
        const int n = n0 + ns + s * 8;
        const float* Xp = X + ((size_t)n * AB_ + ab) * BIN_;
        float acc = bv;
#pragma unroll
        for (int i = 0; i < BIN_; ++i) acc = fmaf(Xp[i], wv[i], acc);
        OUT[((size_t)n * AB_ + ab) * BOUT_ + o] = acc;
    }
}

extern "C" void kernel_launch(void* const* d_in, const int* in_sizes, int n_in,
                              void* d_out, int out_size, void* d_ws, size_t ws_size,
                              hipStream_t stream) {
    const float* x0 = (const float*)d_in[0];
    const float* w0 = (const float*)d_in[1];
    const float* x2 = (const float*)d_in[2];
    const float* w2 = (const float*)d_in[3];
    const float* x4 = (const float*)d_in[4];
    const float* w4 = (const float*)d_in[5];
    const float* x6 = (const float*)d_in[6];
    const float* w6 = (const float*)d_in[7];
    const float* x8 = (const float*)d_in[8];
    const float* w8 = (const float*)d_in[9];
    const float* bias = (const float*)d_in[10];
    float* out = (float*)d_out;

    const size_t per = (size_t)B_ * AB_ * BOUT_;
    size_t off0 = 0;
    size_t off2 = off0 + per * 1;
    size_t off4 = off2 + per * 25;
    size_t off6 = off4 + per * 81;
    size_t off8 = off6 + per * 169;

    const int S = B_ * AB_;  // 6144 slices

    //       NSH SPB BLOCK          grid
    conv_pk<17, 1, 576><<<S,     576, 0, stream>>>(x8, w8, out + off8);
    conv_pk<13, 1, 448><<<S,     448, 0, stream>>>(x6, w6, out + off6);
    conv_pk< 9, 2, 576><<<S / 2, 576, 0, stream>>>(x4, w4, out + off4);
    conv_pk< 5, 4, 640><<<S / 4, 640, 0, stream>>>(x2, w2, out + off2);
    conv_l0_kernel<<<(B_ / 64) * AB_, 256, 0, stream>>>(x0, w0, bias, out + off0);
}